// Round 16
// baseline (169.223 us; speedup 1.0000x reference)
//
#include <hip/hip_runtime.h>
#include <float.h>

#define D    64
#define K    512
#define HW   4096      // 64*64
#define NPIX 131072    // 32*4096
#define GT_M 1.5e-4f   // m-units gap; key-noise 2*3.1e-5 + mfma err ~2e-6 -> 2x margin

// ===== MFMA-path ws layout (bytes) =====
#define OFF_CK    0u          // float ck[512]                    (2048)
#define OFF_CBFH  2048u       // ushort cbfh[64*512] frag-packed, NEGATED e, hi
#define OFF_CBFL  67584u      // ushort cbfl[64*512]  NEGATED e, lo
#define OFF_T1    133120u     // float t1[NPIX]                   (524288)
#define OFF_XH    657408u     // ushort xh[8][NPIX][8] chunk-major(16777216)
#define OFF_XL    17434624u   // ushort xl[8][NPIX][8]            (16777216)
#define OFF_IDX   34211840u   // int idx[NPIX]                    (524288)
#define OFF_CNT   34736128u   // int count                        (4)
#define OFF_LIST  34736132u   // int list[NPIX]                   (524288)
#define OFF_CKM   35260420u   // float ckm[512] = 0.5 + ck/2      (2048)
#define WS_NEED   35262468u

typedef __attribute__((ext_vector_type(8))) short bf16x8;
typedef __attribute__((ext_vector_type(4))) float f32x4;

__device__ __forceinline__ unsigned short bf16_rne(float f) {
    unsigned u = __float_as_uint(f);
    return (unsigned short)((u + 0x7FFFu + ((u >> 16) & 1u)) >> 16);
}
__device__ __forceinline__ float bf16_back(unsigned short h) {
    return __uint_as_float(((unsigned)h) << 16);
}

// ck[k] = numpy sum(cb*cb, axis=0): sequential adds over d, squares pre-rounded.
// ckm[k] = 0.5 + ck/2 (filter-side only). Packs bf16 hi/lo of NEGATED e:
//   pos(tile=k>>4, ks=d>>5, g=(d>>3)&3, n=k&15, j=d&7) = (tile*2+ks)*512 + g*128 + n*8 + j
__global__ void vq_prep_m(const float* __restrict__ cb, float* __restrict__ ck,
                          float* __restrict__ ckm,
                          unsigned short* __restrict__ cbfh, unsigned short* __restrict__ cbfl,
                          int* __restrict__ count) {
#pragma clang fp contract(off)
    const int k = blockIdx.x * 128 + threadIdx.x;
    if (k == 0) *count = 0;
    float s = 0.f;
    for (int d = 0; d < D; ++d) {
        const float e  = cb[d * K + k];
        const float e2 = e * e;
        s = s + e2;
        const float en = -e;
        const unsigned short h = bf16_rne(en);
        const unsigned short l = bf16_rne(en - bf16_back(h));
        const int pos = ((k >> 4) * 2 + (d >> 5)) * 512 + ((d >> 3) & 3) * 128 + (k & 15) * 8 + (d & 7);
        cbfh[pos] = h;
        cbfl[pos] = l;
    }
    ck[k]  = s;
    ckm[k] = 0.5f + 0.5f * s;
}

// Per pixel: exact numpy t1 (pairwise 8-acc) + bf16 hi/lo split of x.
// CHUNK-MAJOR [c][p][8] output. (verbatim round-9)
__global__ __launch_bounds__(256) void vq_pre(const float* __restrict__ enc,
        float* __restrict__ t1a, unsigned short* __restrict__ xh,
        unsigned short* __restrict__ xl) {
    const int p  = blockIdx.x * 256 + threadIdx.x;
    const int b  = p >> 12;
    const int hw = p & 4095;
    const float* ep = enc + (size_t)b * (D * HW) + hw;
    float x[D];
    #pragma unroll
    for (int d = 0; d < D; ++d) x[d] = ep[(size_t)d * HW];

    float t1;
    {
#pragma clang fp contract(off)
        float r[8];
        #pragma unroll
        for (int j = 0; j < 8; ++j) r[j] = x[j] * x[j];
        #pragma unroll
        for (int i = 8; i < 64; i += 8) {
            #pragma unroll
            for (int j = 0; j < 8; ++j) {
                const float v2 = x[i + j] * x[i + j];
                r[j] = r[j] + v2;
            }
        }
        t1 = ((r[0] + r[1]) + (r[2] + r[3])) + ((r[4] + r[5]) + (r[6] + r[7]));
    }
    t1a[p] = t1;

    #pragma unroll
    for (int c = 0; c < 8; ++c) {
        unsigned short hs[8], ls[8];
        #pragma unroll
        for (int j = 0; j < 8; ++j) {
            const float v = x[c * 8 + j];
            const unsigned short h = bf16_rne(v);
            hs[j] = h;
            ls[j] = bf16_rne(v - bf16_back(h));
        }
        uint4 hv, lv;
        hv.x = (unsigned)hs[0] | ((unsigned)hs[1] << 16);
        hv.y = (unsigned)hs[2] | ((unsigned)hs[3] << 16);
        hv.z = (unsigned)hs[4] | ((unsigned)hs[5] << 16);
        hv.w = (unsigned)hs[6] | ((unsigned)hs[7] << 16);
        lv.x = (unsigned)ls[0] | ((unsigned)ls[1] << 16);
        lv.y = (unsigned)ls[2] | ((unsigned)ls[3] << 16);
        lv.z = (unsigned)ls[4] | ((unsigned)ls[5] << 16);
        lv.w = (unsigned)ls[6] | ((unsigned)ls[7] << 16);
        *reinterpret_cast<uint4*>(xh + ((size_t)c * NPIX + p) * 8) = hv;
        *reinterpret_cast<uint4*>(xl + ((size_t)c * NPIX + p) * 8) = lv;
    }
}

// MFMA filter (round-15 + surgical latency fixes):
//  - ckm staged in LDS once (inner loop has NO global loads in its chain)
//  - 512-thread blocks: 8 waves x 16 px = 128 px/block -> staging traffic,
//    barriers, and L2 cb contention per pixel halve
//  - 8-tile inner loop fully unrolled for deep ds_read pipelining
// m = 0.5 + ck/2 - x.e via 6 MFMAs on negated-e frags; sortable key packs the
// 9-bit code index into the mantissa; gap < GT_M -> exact-numpy refine.
__global__ __launch_bounds__(512) void vq_mfma(const unsigned short* __restrict__ xh,
        const unsigned short* __restrict__ xl, const unsigned short* __restrict__ cbfh,
        const unsigned short* __restrict__ cbfl, const float* __restrict__ ckm,
        int* __restrict__ idx, int* __restrict__ count, int* __restrict__ list) {
    __shared__ unsigned short sh[8192];   // 16 KB: 8 tiles x 2 ksteps x 512
    __shared__ unsigned short sl[8192];   // 16 KB
    __shared__ float sck[512];            // 2 KB: ckm staged once

    const int t    = threadIdx.x;
    const int lane = t & 63;
    const int wu   = __builtin_amdgcn_readfirstlane(t >> 6);   // 0..7
    const int P0   = blockIdx.x * 128 + wu * 16;
    const int n    = lane & 15;          // A-row / B-col / D-col index
    const int g    = lane >> 4;          // k-block / D-row group
    const int pp   = P0 + n;

    if (t < 512) sck[t] = ckm[t];

    const bf16x8 ah0 = *(const bf16x8*)(xh + ((size_t)g       * NPIX + pp) * 8);
    const bf16x8 ah1 = *(const bf16x8*)(xh + ((size_t)(g + 4) * NPIX + pp) * 8);
    const bf16x8 al0 = *(const bf16x8*)(xl + ((size_t)g       * NPIX + pp) * 8);
    const bf16x8 al1 = *(const bf16x8*)(xl + ((size_t)(g + 4) * NPIX + pp) * 8);

    float best[4], best2[4];
    #pragma unroll
    for (int i = 0; i < 4; ++i) { best[i] = FLT_MAX; best2[i] = FLT_MAX; }

    #pragma unroll 1
    for (int G = 0; G < 4; ++G) {
        // stage 8 tiles of frag-packed -e hi/lo (16 KB each), coalesced uint4
        {
            const uint4* srcH = (const uint4*)(cbfh + G * 8192);
            const uint4* srcL = (const uint4*)(cbfl + G * 8192);
            uint4* dstH = (uint4*)sh;
            uint4* dstL = (uint4*)sl;
            #pragma unroll
            for (int i = 0; i < 2; ++i) {
                dstH[t + i * 512] = srcH[t + i * 512];
                dstL[t + i * 512] = srcL[t + i * 512];
            }
        }
        __syncthreads();

        #pragma unroll
        for (int tl = 0; tl < 8; ++tl) {
            const int tile = G * 8 + tl;
            const int b0 = tl * 1024 + g * 128 + n * 8;
            const bf16x8 bh0 = *(const bf16x8*)(sh + b0);
            const bf16x8 bh1 = *(const bf16x8*)(sh + b0 + 512);
            const bf16x8 bl0 = *(const bf16x8*)(sl + b0);
            const bf16x8 bl1 = *(const bf16x8*)(sl + b0 + 512);
            const float ckmv = sck[tile * 16 + n];
            const unsigned kidx = (unsigned)(tile * 16 + n);

            f32x4 acc0 = {0.f, 0.f, 0.f, 0.f};
            f32x4 acc1 = {0.f, 0.f, 0.f, 0.f};
            acc0 = __builtin_amdgcn_mfma_f32_16x16x32_bf16(al0, bh0, acc0, 0, 0, 0);
            acc1 = __builtin_amdgcn_mfma_f32_16x16x32_bf16(al1, bh1, acc1, 0, 0, 0);
            acc0 = __builtin_amdgcn_mfma_f32_16x16x32_bf16(ah0, bl0, acc0, 0, 0, 0);
            acc1 = __builtin_amdgcn_mfma_f32_16x16x32_bf16(ah1, bl1, acc1, 0, 0, 0);
            acc0 = __builtin_amdgcn_mfma_f32_16x16x32_bf16(ah0, bh0, acc0, 0, 0, 0);
            acc1 = __builtin_amdgcn_mfma_f32_16x16x32_bf16(ah1, bh1, acc1, 0, 0, 0);

            #pragma unroll
            for (int i = 0; i < 4; ++i) {
                const float m   = (acc0[i] + acc1[i]) + ckmv;         // in [0.36,0.65]
                const float key = __uint_as_float(
                    (__float_as_uint(m) & 0xFFFFFE00u) | kidx);
                const float nb  = fminf(best[i], key);
                best2[i] = fminf(best2[i], fmaxf(best[i], key));
                best[i]  = nb;
            }
        }
        __syncthreads();
    }

    // merge the 16 lanes of each row-group: keys are self-ordering
    #pragma unroll
    for (int off = 1; off < 16; off <<= 1) {
        #pragma unroll
        for (int i = 0; i < 4; ++i) {
            const float ob  = __shfl_xor(best[i],  off, 16);
            const float ob2 = __shfl_xor(best2[i], off, 16);
            best2[i] = fminf(fminf(best2[i], ob2), fmaxf(best[i], ob));
            best[i]  = fminf(best[i], ob);
        }
    }

    if (n == 0) {
        #pragma unroll
        for (int i = 0; i < 4; ++i) {
            const int p = P0 + g * 4 + i;
            idx[p] = (int)(__float_as_uint(best[i]) & 511u);
            if (best2[i] - best[i] < GT_M) {
                const int slot = atomicAdd(count, 1);
                list[slot] = p;
            }
        }
    }
}

// Exact numpy rescore for near-tie pixels (round-9 verbatim, uses t1a).
__global__ __launch_bounds__(256) void vq_refine(const float* __restrict__ enc,
        const float* __restrict__ cb, const float* __restrict__ ck,
        const float* __restrict__ t1a, const int* __restrict__ count,
        const int* __restrict__ list, int* __restrict__ idx) {
    const int nref = *count;
    const int lane = threadIdx.x & 63;
    const int gw   = (int)((blockIdx.x * blockDim.x + threadIdx.x) >> 6);
    const int nw   = (int)((gridDim.x * blockDim.x) >> 6);
    for (int r = gw; r < nref; r += nw) {
        const int p  = list[r];
        const int b  = p >> 12;
        const int hw = p & 4095;
        const float* xp = enc + (size_t)b * (D * HW) + hw;
        const float xown = xp[(size_t)lane * HW];   // lane holds x[lane]
        const float t1 = t1a[p];
        float acc[8];
        #pragma unroll
        for (int j = 0; j < 8; ++j) acc[j] = 0.f;
        const float* cbl = cb + lane * 8;
        #pragma unroll 16
        for (int d = 0; d < D; ++d) {
            const float xd = __shfl(xown, d);
            const float4 c0 = *(const float4*)(cbl + (size_t)d * K);
            const float4 c1 = *(const float4*)(cbl + (size_t)d * K + 4);
            acc[0] = fmaf(xd, c0.x, acc[0]);
            acc[1] = fmaf(xd, c0.y, acc[1]);
            acc[2] = fmaf(xd, c0.z, acc[2]);
            acc[3] = fmaf(xd, c0.w, acc[3]);
            acc[4] = fmaf(xd, c1.x, acc[4]);
            acc[5] = fmaf(xd, c1.y, acc[5]);
            acc[6] = fmaf(xd, c1.z, acc[6]);
            acc[7] = fmaf(xd, c1.w, acc[7]);
        }
        float bv = FLT_MAX;
        int bI = 0x7fffffff;
        #pragma unroll
        for (int j = 0; j < 8; ++j) {
            const float u    = fmaf(-2.0f, acc[j], t1);
            const float dist = u + ck[lane * 8 + j];
            if (dist < bv) { bv = dist; bI = lane * 8 + j; }
        }
        #pragma unroll
        for (int off = 32; off > 0; off >>= 1) {
            const float ov = __shfl_down(bv, off);
            const int   oi = __shfl_down(bI, off);
            if (ov < bv || (ov == bv && oi < bI)) { bv = ov; bI = oi; }
        }
        if (lane == 0) idx[p] = bI;
    }
}

// ===== scalar fallback (round-7, proven 128 us) =====
__global__ void vq_prep_s(const float* __restrict__ cb, float* __restrict__ ck) {
#pragma clang fp contract(off)
    const int k = threadIdx.x;
    float s = 0.f;
    for (int d = 0; d < D; ++d) {
        const float e  = cb[d * K + k];
        const float e2 = e * e;
        s = s + e2;
    }
    ck[k] = s;
}

__global__ __launch_bounds__(256, 8) void vq_main_s(const float* __restrict__ enc,
        const float* __restrict__ cb, const float* __restrict__ ck,
        int* __restrict__ idx) {
    __shared__ float xs[D][64];
    __shared__ float bvs[3][64];
    __shared__ int   bis[3][64];

    const int t    = threadIdx.x;
    const int lane = t & 63;
    const int wu   = __builtin_amdgcn_readfirstlane(t >> 6);
    const int base = blockIdx.x * 64;
    const int b    = base >> 12;
    const int hw0  = base & 4095;
    const float* ep = enc + (size_t)b * (D * HW) + hw0;

    #pragma unroll
    for (int i = 0; i < 16; ++i) {
        const int id  = t + i * 256;
        xs[id >> 6][id & 63] = ep[(size_t)(id >> 6) * HW + (id & 63)];
    }
    __syncthreads();

    float t1;
    {
#pragma clang fp contract(off)
        float r[8];
        #pragma unroll
        for (int j = 0; j < 8; ++j) { const float v = xs[j][lane]; r[j] = v * v; }
        #pragma unroll
        for (int i = 8; i < 64; i += 8) {
            #pragma unroll
            for (int j = 0; j < 8; ++j) {
                const float v = xs[i + j][lane]; const float v2 = v * v; r[j] = r[j] + v2;
            }
        }
        t1 = ((r[0] + r[1]) + (r[2] + r[3])) + ((r[4] + r[5]) + (r[6] + r[7]));
    }

    float best = FLT_MAX;
    int besti  = 0x7fffffff;
    const int kbase = wu * (K / 4);
    #pragma unroll 1
    for (int tt = 0; tt < 8; ++tt) {
        const int k0 = kbase + tt * 16;
        float acc[16];
        #pragma unroll
        for (int j = 0; j < 16; ++j) acc[j] = 0.f;
        #pragma unroll 8
        for (int d = 0; d < D; ++d) {
            const float xv = xs[d][lane];
            const float* cbrow = cb + d * K + k0;
            #pragma unroll
            for (int j = 0; j < 16; ++j) acc[j] = fmaf(xv, cbrow[j], acc[j]);
        }
        #pragma unroll
        for (int j = 0; j < 16; ++j) {
            const float u    = fmaf(-2.0f, acc[j], t1);
            const float dist = u + ck[k0 + j];
            if (dist < best) { best = dist; besti = k0 + j; }
        }
    }

    if (wu > 0) { bvs[wu - 1][lane] = best; bis[wu - 1][lane] = besti; }
    __syncthreads();
    if (wu == 0) {
        #pragma unroll
        for (int q = 0; q < 3; ++q) {
            const float ov = bvs[q][lane];
            const int   oi = bis[q][lane];
            if (ov < best) { best = ov; besti = oi; }
        }
        idx[base + lane] = besti;
    }
}

__global__ void vq_out(const float* __restrict__ cb, const int* __restrict__ idx,
                       float* __restrict__ out) {
    const int o = (blockIdx.x * 256 + threadIdx.x) * 4;
    const int d = (o >> 12) & 63;
    const int bhw = ((o >> 18) << 12) | (o & 4095);
    const int4 iv = *reinterpret_cast<const int4*>(idx + bhw);
    float4 v;
    v.x = cb[d * K + iv.x];
    v.y = cb[d * K + iv.y];
    v.z = cb[d * K + iv.z];
    v.w = cb[d * K + iv.w];
    *reinterpret_cast<float4*>(out + o) = v;
}

extern "C" void kernel_launch(void* const* d_in, const int* in_sizes, int n_in,
                              void* d_out, int out_size, void* d_ws, size_t ws_size,
                              hipStream_t stream) {
    const float* enc = (const float*)d_in[0];
    const float* cb  = (const float*)d_in[1];
    float* out = (float*)d_out;
    char* ws = (char*)d_ws;

    if (ws_size >= (size_t)WS_NEED) {
        float*          ck   = (float*)(ws + OFF_CK);
        float*          ckm  = (float*)(ws + OFF_CKM);
        unsigned short* cbfh = (unsigned short*)(ws + OFF_CBFH);
        unsigned short* cbfl = (unsigned short*)(ws + OFF_CBFL);
        float*          t1a  = (float*)(ws + OFF_T1);
        unsigned short* xh   = (unsigned short*)(ws + OFF_XH);
        unsigned short* xl   = (unsigned short*)(ws + OFF_XL);
        int*            idx  = (int*)(ws + OFF_IDX);
        int*            cnt  = (int*)(ws + OFF_CNT);
        int*            list = (int*)(ws + OFF_LIST);

        vq_prep_m<<<4, 128, 0, stream>>>(cb, ck, ckm, cbfh, cbfl, cnt);
        vq_pre<<<NPIX / 256, 256, 0, stream>>>(enc, t1a, xh, xl);
        vq_mfma<<<NPIX / 128, 512, 0, stream>>>(xh, xl, cbfh, cbfl, ckm, idx, cnt, list);
        vq_refine<<<1024, 256, 0, stream>>>(enc, cb, ck, t1a, cnt, list, idx);
        vq_out<<<out_size / 1024, 256, 0, stream>>>(cb, idx, out);
    } else {
        float* ck  = (float*)ws;
        int*   idx = (int*)(ws + 2048);
        vq_prep_s<<<1, K, 0, stream>>>(cb, ck);
        vq_main_s<<<NPIX / 64, 256, 0, stream>>>(enc, cb, ck, idx);
        vq_out<<<out_size / 1024, 256, 0, stream>>>(cb, idx, out);
    }
}

// Round 17
// 122.025 us; speedup vs baseline: 1.3868x; 1.3868x over previous
//
#include <hip/hip_runtime.h>
#include <float.h>

#define D    64
#define K    512
#define HW   4096      // 64*64
#define NPIX 131072    // 32*4096
#define KT   16
#define GT   8e-5f     // dist-units gap threshold >= 2x |approx-numpy| bound (~2e-5)

// ===== MFMA-path ws layout (bytes) — round-9 layout =====
#define OFF_CK    0u          // float ck[512]                    (2048)
#define OFF_CBFH  2048u       // ushort cbfh[64*512] frag-packed  (65536)
#define OFF_CBFL  67584u      // ushort cbfl[64*512]              (65536)
#define OFF_T1    133120u     // float t1[NPIX]                   (524288)
#define OFF_XH    657408u     // ushort xh[8][NPIX][8] chunk-major(16777216)
#define OFF_XL    17434624u   // ushort xl[8][NPIX][8]            (16777216)
#define OFF_IDX   34211840u   // int idx[NPIX]                    (524288)
#define OFF_CNT   34736128u   // int count                        (4)
#define OFF_LIST  34736132u   // int list[NPIX]                   (524288)
#define WS_NEED   35260420u

typedef __attribute__((ext_vector_type(8))) short bf16x8;
typedef __attribute__((ext_vector_type(4))) float f32x4;

__device__ __forceinline__ unsigned short bf16_rne(float f) {
    unsigned u = __float_as_uint(f);
    return (unsigned short)((u + 0x7FFFu + ((u >> 16) & 1u)) >> 16);
}
__device__ __forceinline__ float bf16_back(unsigned short h) {
    return __uint_as_float(((unsigned)h) << 16);
}

// ck[k] = numpy sum(cb*cb, axis=0): sequential adds over d, squares pre-rounded.
// Packs cb into bf16 hi/lo fragment layout (round-9 verbatim math; 4-block grid):
//   pos(tile=k>>4, ks=d>>5, g=(d>>3)&3, n=k&15, j=d&7) = (tile*2+ks)*512 + g*128 + n*8 + j
__global__ void vq_prep_m(const float* __restrict__ cb, float* __restrict__ ck,
                          unsigned short* __restrict__ cbfh, unsigned short* __restrict__ cbfl,
                          int* __restrict__ count) {
#pragma clang fp contract(off)
    const int k = blockIdx.x * 128 + threadIdx.x;
    if (k == 0) *count = 0;
    float s = 0.f;
    for (int d = 0; d < D; ++d) {
        const float e  = cb[d * K + k];
        const float e2 = e * e;
        s = s + e2;
        const unsigned short h = bf16_rne(e);
        const unsigned short l = bf16_rne(e - bf16_back(h));
        const int pos = ((k >> 4) * 2 + (d >> 5)) * 512 + ((d >> 3) & 3) * 128 + (k & 15) * 8 + (d & 7);
        cbfh[pos] = h;
        cbfl[pos] = l;
    }
    ck[k] = s;
}

// Per pixel: exact numpy t1 (pairwise 8-acc) + bf16 hi/lo split of x.
// Output layout CHUNK-MAJOR [c][p][8] so stores are dense uint4 across threads.
// (round-9 verbatim)
__global__ __launch_bounds__(256) void vq_pre(const float* __restrict__ enc,
        float* __restrict__ t1a, unsigned short* __restrict__ xh,
        unsigned short* __restrict__ xl) {
    const int p  = blockIdx.x * 256 + threadIdx.x;
    const int b  = p >> 12;
    const int hw = p & 4095;
    const float* ep = enc + (size_t)b * (D * HW) + hw;
    float x[D];
    #pragma unroll
    for (int d = 0; d < D; ++d) x[d] = ep[(size_t)d * HW];

    float t1;
    {
#pragma clang fp contract(off)
        float r[8];
        #pragma unroll
        for (int j = 0; j < 8; ++j) r[j] = x[j] * x[j];
        #pragma unroll
        for (int i = 8; i < 64; i += 8) {
            #pragma unroll
            for (int j = 0; j < 8; ++j) {
                const float v2 = x[i + j] * x[i + j];
                r[j] = r[j] + v2;
            }
        }
        t1 = ((r[0] + r[1]) + (r[2] + r[3])) + ((r[4] + r[5]) + (r[6] + r[7]));
    }
    t1a[p] = t1;

    #pragma unroll
    for (int c = 0; c < 8; ++c) {
        unsigned short hs[8], ls[8];
        #pragma unroll
        for (int j = 0; j < 8; ++j) {
            const float v = x[c * 8 + j];
            const unsigned short h = bf16_rne(v);
            hs[j] = h;
            ls[j] = bf16_rne(v - bf16_back(h));
        }
        uint4 hv, lv;
        hv.x = (unsigned)hs[0] | ((unsigned)hs[1] << 16);
        hv.y = (unsigned)hs[2] | ((unsigned)hs[3] << 16);
        hv.z = (unsigned)hs[4] | ((unsigned)hs[5] << 16);
        hv.w = (unsigned)hs[6] | ((unsigned)hs[7] << 16);
        lv.x = (unsigned)ls[0] | ((unsigned)ls[1] << 16);
        lv.y = (unsigned)ls[2] | ((unsigned)ls[3] << 16);
        lv.z = (unsigned)ls[4] | ((unsigned)ls[5] << 16);
        lv.w = (unsigned)ls[6] | ((unsigned)ls[7] << 16);
        *reinterpret_cast<uint4*>(xh + ((size_t)c * NPIX + p) * 8) = hv;
        *reinterpret_cast<uint4*>(xl + ((size_t)c * NPIX + p) * 8) = lv;
    }
}

// MFMA filter: per wave 16 pixels x 512 codes. cb frags staged in LDS in 4
// groups of 8 tiles (4 waves share one L2 read). dot = xh*eh + xh*el + xl*eh.
// (round-9 verbatim -- the 77 us champion; R13-R16 established that every
// "slimmer" variant is strictly slower)
__global__ __launch_bounds__(256) void vq_mfma(const unsigned short* __restrict__ xh,
        const unsigned short* __restrict__ xl, const unsigned short* __restrict__ cbfh,
        const unsigned short* __restrict__ cbfl, const float* __restrict__ t1a,
        const float* __restrict__ ck, int* __restrict__ idx,
        int* __restrict__ count, int* __restrict__ list) {
    __shared__ unsigned short sh[8192];   // 16 KB: 8 tiles x 2 ksteps x 512
    __shared__ unsigned short sl[8192];   // 16 KB

    const int t    = threadIdx.x;
    const int lane = t & 63;
    const int wu   = __builtin_amdgcn_readfirstlane(t >> 6);
    const int P0   = blockIdx.x * 64 + wu * 16;
    const int n    = lane & 15;          // A-row / B-col / D-col index
    const int g    = lane >> 4;          // k-block / D-row group
    const int pp   = P0 + n;

    const bf16x8 ah0 = *(const bf16x8*)(xh + ((size_t)g       * NPIX + pp) * 8);
    const bf16x8 ah1 = *(const bf16x8*)(xh + ((size_t)(g + 4) * NPIX + pp) * 8);
    const bf16x8 al0 = *(const bf16x8*)(xl + ((size_t)g       * NPIX + pp) * 8);
    const bf16x8 al1 = *(const bf16x8*)(xl + ((size_t)(g + 4) * NPIX + pp) * 8);
    const f32x4 t1v = *(const f32x4*)(t1a + P0 + g * 4);

    float best[4], best2[4];
    int besti[4];
    #pragma unroll
    for (int i = 0; i < 4; ++i) { best[i] = FLT_MAX; best2[i] = FLT_MAX; besti[i] = 0x7fffffff; }

    #pragma unroll 1
    for (int G = 0; G < 4; ++G) {
        // stage 8 tiles of frag-packed cb (16 KB h + 16 KB l), coalesced uint4
        {
            const uint4* srcH = (const uint4*)(cbfh + G * 8192);
            const uint4* srcL = (const uint4*)(cbfl + G * 8192);
            uint4* dstH = (uint4*)sh;
            uint4* dstL = (uint4*)sl;
            #pragma unroll
            for (int i = 0; i < 4; ++i) {
                dstH[t + i * 256] = srcH[t + i * 256];
                dstL[t + i * 256] = srcL[t + i * 256];
            }
        }
        __syncthreads();

        #pragma unroll 2
        for (int tl = 0; tl < 8; ++tl) {
            const int tile = G * 8 + tl;
            const int b0 = tl * 1024 + g * 128 + n * 8;
            const bf16x8 bh0 = *(const bf16x8*)(sh + b0);
            const bf16x8 bh1 = *(const bf16x8*)(sh + b0 + 512);
            const bf16x8 bl0 = *(const bf16x8*)(sl + b0);
            const bf16x8 bl1 = *(const bf16x8*)(sl + b0 + 512);
            const float ckv = ck[tile * 16 + n];

            f32x4 acc0 = {0.f, 0.f, 0.f, 0.f};
            f32x4 acc1 = {0.f, 0.f, 0.f, 0.f};
            acc0 = __builtin_amdgcn_mfma_f32_16x16x32_bf16(al0, bh0, acc0, 0, 0, 0);
            acc1 = __builtin_amdgcn_mfma_f32_16x16x32_bf16(al1, bh1, acc1, 0, 0, 0);
            acc0 = __builtin_amdgcn_mfma_f32_16x16x32_bf16(ah0, bl0, acc0, 0, 0, 0);
            acc1 = __builtin_amdgcn_mfma_f32_16x16x32_bf16(ah1, bl1, acc1, 0, 0, 0);
            acc0 = __builtin_amdgcn_mfma_f32_16x16x32_bf16(ah0, bh0, acc0, 0, 0, 0);
            acc1 = __builtin_amdgcn_mfma_f32_16x16x32_bf16(ah1, bh1, acc1, 0, 0, 0);

            const int kbase = tile * 16 + n;
            #pragma unroll
            for (int i = 0; i < 4; ++i) {
                const float dot  = acc0[i] + acc1[i];
                const float u    = fmaf(-2.0f, dot, t1v[i]);
                const float dist = u + ckv;
                if (dist < best[i]) { best2[i] = best[i]; best[i] = dist; besti[i] = kbase; }
                else if (dist == best[i]) { best2[i] = dist; if (kbase < besti[i]) besti[i] = kbase; }
                else if (dist < best2[i]) { best2[i] = dist; }
            }
        }
        __syncthreads();
    }

    // merge the 16 lanes of each row-group (each holds different code columns)
    #pragma unroll
    for (int off = 1; off < 16; off <<= 1) {
        #pragma unroll
        for (int i = 0; i < 4; ++i) {
            const float ob  = __shfl_xor(best[i],  off, 16);
            const float ob2 = __shfl_xor(best2[i], off, 16);
            const int   obi = __shfl_xor(besti[i], off, 16);
            if (ob < best[i])      { best2[i] = fminf(best[i], ob2); best[i] = ob; besti[i] = obi; }
            else if (ob > best[i]) { best2[i] = fminf(best2[i], ob); }
            else { besti[i] = min(besti[i], obi); best2[i] = fminf(fminf(best2[i], ob2), ob); }
        }
    }

    if (n == 0) {
        #pragma unroll
        for (int i = 0; i < 4; ++i) {
            const int p = P0 + g * 4 + i;
            idx[p] = besti[i];
            if (best2[i] - best[i] < GT) {
                const int slot = atomicAdd(count, 1);
                list[slot] = p;
            }
        }
    }
}

// Exact numpy rescore for near-tie pixels (round-9 verbatim, uses t1a).
__global__ __launch_bounds__(256) void vq_refine(const float* __restrict__ enc,
        const float* __restrict__ cb, const float* __restrict__ ck,
        const float* __restrict__ t1a, const int* __restrict__ count,
        const int* __restrict__ list, int* __restrict__ idx) {
    const int nref = *count;
    const int lane = threadIdx.x & 63;
    const int gw   = (int)((blockIdx.x * blockDim.x + threadIdx.x) >> 6);
    const int nw   = (int)((gridDim.x * blockDim.x) >> 6);
    for (int r = gw; r < nref; r += nw) {
        const int p  = list[r];
        const int b  = p >> 12;
        const int hw = p & 4095;
        const float* xp = enc + (size_t)b * (D * HW) + hw;
        const float xown = xp[(size_t)lane * HW];   // lane holds x[lane]
        const float t1 = t1a[p];
        float acc[8];
        #pragma unroll
        for (int j = 0; j < 8; ++j) acc[j] = 0.f;
        const float* cbl = cb + lane * 8;
        #pragma unroll 16
        for (int d = 0; d < D; ++d) {
            const float xd = __shfl(xown, d);
            const float4 c0 = *(const float4*)(cbl + (size_t)d * K);
            const float4 c1 = *(const float4*)(cbl + (size_t)d * K + 4);
            acc[0] = fmaf(xd, c0.x, acc[0]);
            acc[1] = fmaf(xd, c0.y, acc[1]);
            acc[2] = fmaf(xd, c0.z, acc[2]);
            acc[3] = fmaf(xd, c0.w, acc[3]);
            acc[4] = fmaf(xd, c1.x, acc[4]);
            acc[5] = fmaf(xd, c1.y, acc[5]);
            acc[6] = fmaf(xd, c1.z, acc[6]);
            acc[7] = fmaf(xd, c1.w, acc[7]);
        }
        float bv = FLT_MAX;
        int bI = 0x7fffffff;
        #pragma unroll
        for (int j = 0; j < 8; ++j) {
            const float u    = fmaf(-2.0f, acc[j], t1);
            const float dist = u + ck[lane * 8 + j];
            if (dist < bv) { bv = dist; bI = lane * 8 + j; }
        }
        #pragma unroll
        for (int off = 32; off > 0; off >>= 1) {
            const float ov = __shfl_down(bv, off);
            const int   oi = __shfl_down(bI, off);
            if (ov < bv || (ov == bv && oi < bI)) { bv = ov; bI = oi; }
        }
        if (lane == 0) idx[p] = bI;
    }
}

// ===== scalar fallback (round-7, proven 128 us) =====
__global__ void vq_prep_s(const float* __restrict__ cb, float* __restrict__ ck) {
#pragma clang fp contract(off)
    const int k = threadIdx.x;
    float s = 0.f;
    for (int d = 0; d < D; ++d) {
        const float e  = cb[d * K + k];
        const float e2 = e * e;
        s = s + e2;
    }
    ck[k] = s;
}

__global__ __launch_bounds__(256, 8) void vq_main_s(const float* __restrict__ enc,
        const float* __restrict__ cb, const float* __restrict__ ck,
        int* __restrict__ idx) {
    __shared__ float xs[D][64];
    __shared__ float bvs[3][64];
    __shared__ int   bis[3][64];

    const int t    = threadIdx.x;
    const int lane = t & 63;
    const int wu   = __builtin_amdgcn_readfirstlane(t >> 6);
    const int base = blockIdx.x * 64;
    const int b    = base >> 12;
    const int hw0  = base & 4095;
    const float* ep = enc + (size_t)b * (D * HW) + hw0;

    #pragma unroll
    for (int i = 0; i < 16; ++i) {
        const int id  = t + i * 256;
        xs[id >> 6][id & 63] = ep[(size_t)(id >> 6) * HW + (id & 63)];
    }
    __syncthreads();

    float t1;
    {
#pragma clang fp contract(off)
        float r[8];
        #pragma unroll
        for (int j = 0; j < 8; ++j) { const float v = xs[j][lane]; r[j] = v * v; }
        #pragma unroll
        for (int i = 8; i < 64; i += 8) {
            #pragma unroll
            for (int j = 0; j < 8; ++j) {
                const float v = xs[i + j][lane]; const float v2 = v * v; r[j] = r[j] + v2;
            }
        }
        t1 = ((r[0] + r[1]) + (r[2] + r[3])) + ((r[4] + r[5]) + (r[6] + r[7]));
    }

    float best = FLT_MAX;
    int besti  = 0x7fffffff;
    const int kbase = wu * (K / 4);
    #pragma unroll 1
    for (int tt = 0; tt < 8; ++tt) {
        const int k0 = kbase + tt * KT;
        float acc[KT];
        #pragma unroll
        for (int j = 0; j < KT; ++j) acc[j] = 0.f;
        #pragma unroll 8
        for (int d = 0; d < D; ++d) {
            const float xv = xs[d][lane];
            const float* cbrow = cb + d * K + k0;
            #pragma unroll
            for (int j = 0; j < KT; ++j) acc[j] = fmaf(xv, cbrow[j], acc[j]);
        }
        #pragma unroll
        for (int j = 0; j < KT; ++j) {
            const float u    = fmaf(-2.0f, acc[j], t1);
            const float dist = u + ck[k0 + j];
            if (dist < best) { best = dist; besti = k0 + j; }
        }
    }

    if (wu > 0) { bvs[wu - 1][lane] = best; bis[wu - 1][lane] = besti; }
    __syncthreads();
    if (wu == 0) {
        #pragma unroll
        for (int q = 0; q < 3; ++q) {
            const float ov = bvs[q][lane];
            const int   oi = bis[q][lane];
            if (ov < best) { best = ov; besti = oi; }
        }
        idx[base + lane] = besti;
    }
}

__global__ void vq_out(const float* __restrict__ cb, const int* __restrict__ idx,
                       float* __restrict__ out) {
    const int o = (blockIdx.x * 256 + threadIdx.x) * 4;
    const int d = (o >> 12) & 63;
    const int bhw = ((o >> 18) << 12) | (o & 4095);
    const int4 iv = *reinterpret_cast<const int4*>(idx + bhw);
    float4 v;
    v.x = cb[d * K + iv.x];
    v.y = cb[d * K + iv.y];
    v.z = cb[d * K + iv.z];
    v.w = cb[d * K + iv.w];
    *reinterpret_cast<float4*>(out + o) = v;
}

extern "C" void kernel_launch(void* const* d_in, const int* in_sizes, int n_in,
                              void* d_out, int out_size, void* d_ws, size_t ws_size,
                              hipStream_t stream) {
    const float* enc = (const float*)d_in[0];
    const float* cb  = (const float*)d_in[1];
    float* out = (float*)d_out;
    char* ws = (char*)d_ws;

    if (ws_size >= (size_t)WS_NEED) {
        float*          ck   = (float*)(ws + OFF_CK);
        unsigned short* cbfh = (unsigned short*)(ws + OFF_CBFH);
        unsigned short* cbfl = (unsigned short*)(ws + OFF_CBFL);
        float*          t1a  = (float*)(ws + OFF_T1);
        unsigned short* xh   = (unsigned short*)(ws + OFF_XH);
        unsigned short* xl   = (unsigned short*)(ws + OFF_XL);
        int*            idx  = (int*)(ws + OFF_IDX);
        int*            cnt  = (int*)(ws + OFF_CNT);
        int*            list = (int*)(ws + OFF_LIST);

        vq_prep_m<<<4, 128, 0, stream>>>(cb, ck, cbfh, cbfl, cnt);
        vq_pre<<<NPIX / 256, 256, 0, stream>>>(enc, t1a, xh, xl);
        vq_mfma<<<NPIX / 64, 256, 0, stream>>>(xh, xl, cbfh, cbfl, t1a, ck, idx, cnt, list);
        vq_refine<<<1024, 256, 0, stream>>>(enc, cb, ck, t1a, cnt, list, idx);
        vq_out<<<out_size / 1024, 256, 0, stream>>>(cb, idx, out);
    } else {
        float* ck  = (float*)ws;
        int*   idx = (int*)(ws + 2048);
        vq_prep_s<<<1, K, 0, stream>>>(cb, ck);
        vq_main_s<<<NPIX / 64, 256, 0, stream>>>(enc, cb, ck, idx);
        vq_out<<<out_size / 1024, 256, 0, stream>>>(cb, idx, out);
    }
}

// Round 18
// 119.705 us; speedup vs baseline: 1.4137x; 1.0194x over previous
//
#include <hip/hip_runtime.h>
#include <float.h>

#define D    64
#define K    512
#define HW   4096      // 64*64
#define NPIX 131072    // 32*4096
#define KT   16
#define GT   8e-5f     // dist-units gap threshold >= 2x |approx-numpy| bound (~2e-5)

// ===== MFMA-path ws layout (bytes) — round-9 layout =====
#define OFF_CK    0u          // float ck[512]                    (2048)
#define OFF_CBFH  2048u       // ushort cbfh[64*512] frag-packed  (65536)
#define OFF_CBFL  67584u      // ushort cbfl[64*512]              (65536)
#define OFF_T1    133120u     // float t1[NPIX]                   (524288)
#define OFF_XH    657408u     // ushort xh[8][NPIX][8] chunk-major(16777216)
#define OFF_XL    17434624u   // ushort xl[8][NPIX][8]            (16777216)
#define OFF_IDX   34211840u   // int idx[NPIX]                    (524288)
#define OFF_CNT   34736128u   // int count                        (4)
#define OFF_LIST  34736132u   // int list[NPIX]                   (524288)
#define WS_NEED   35260420u

typedef __attribute__((ext_vector_type(8))) short bf16x8;
typedef __attribute__((ext_vector_type(4))) float f32x4;

__device__ __forceinline__ unsigned short bf16_rne(float f) {
    unsigned u = __float_as_uint(f);
    return (unsigned short)((u + 0x7FFFu + ((u >> 16) & 1u)) >> 16);
}
__device__ __forceinline__ float bf16_back(unsigned short h) {
    return __uint_as_float(((unsigned)h) << 16);
}

// FUSED prep+pre (single launch; prep's ~4-5 us of whole-GPU serialization now
// hides under pre's memory time — the two halves are independent and the
// kernel boundary before vq_mfma orders everything).
//
// Blocks 0..1  (256 thr): prep — ck[k] = numpy sum(cb*cb,axis=0) (sequential
//   adds over d, squares pre-rounded) + pack cb into bf16 hi/lo fragment
//   layout pos(tile=k>>4, ks=d>>5, g=(d>>3)&3, n=k&15, j=d&7)
//   = (tile*2+ks)*512 + g*128 + n*8 + j.  Thread 0 zeroes count.
// Blocks 2..513 (256 thr): pre — exact numpy t1 (pairwise 8-acc) + bf16
//   hi/lo split of x, CHUNK-MAJOR [c][p][8] uint4 stores. (round-9 verbatim)
__global__ __launch_bounds__(256) void vq_prep_pre(const float* __restrict__ cb,
        const float* __restrict__ enc, float* __restrict__ ck,
        unsigned short* __restrict__ cbfh, unsigned short* __restrict__ cbfl,
        int* __restrict__ count, float* __restrict__ t1a,
        unsigned short* __restrict__ xh, unsigned short* __restrict__ xl) {
    if (blockIdx.x < 2) {
#pragma clang fp contract(off)
        const int k = blockIdx.x * 256 + threadIdx.x;
        if (k == 0) *count = 0;
        float s = 0.f;
        for (int d = 0; d < D; ++d) {
            const float e  = cb[d * K + k];
            const float e2 = e * e;
            s = s + e2;
            const unsigned short h = bf16_rne(e);
            const unsigned short l = bf16_rne(e - bf16_back(h));
            const int pos = ((k >> 4) * 2 + (d >> 5)) * 512 + ((d >> 3) & 3) * 128 + (k & 15) * 8 + (d & 7);
            cbfh[pos] = h;
            cbfl[pos] = l;
        }
        ck[k] = s;
        return;
    }

    const int p  = (blockIdx.x - 2) * 256 + threadIdx.x;
    const int b  = p >> 12;
    const int hw = p & 4095;
    const float* ep = enc + (size_t)b * (D * HW) + hw;
    float x[D];
    #pragma unroll
    for (int d = 0; d < D; ++d) x[d] = ep[(size_t)d * HW];

    float t1;
    {
#pragma clang fp contract(off)
        float r[8];
        #pragma unroll
        for (int j = 0; j < 8; ++j) r[j] = x[j] * x[j];
        #pragma unroll
        for (int i = 8; i < 64; i += 8) {
            #pragma unroll
            for (int j = 0; j < 8; ++j) {
                const float v2 = x[i + j] * x[i + j];
                r[j] = r[j] + v2;
            }
        }
        t1 = ((r[0] + r[1]) + (r[2] + r[3])) + ((r[4] + r[5]) + (r[6] + r[7]));
    }
    t1a[p] = t1;

    #pragma unroll
    for (int c = 0; c < 8; ++c) {
        unsigned short hs[8], ls[8];
        #pragma unroll
        for (int j = 0; j < 8; ++j) {
            const float v = x[c * 8 + j];
            const unsigned short h = bf16_rne(v);
            hs[j] = h;
            ls[j] = bf16_rne(v - bf16_back(h));
        }
        uint4 hv, lv;
        hv.x = (unsigned)hs[0] | ((unsigned)hs[1] << 16);
        hv.y = (unsigned)hs[2] | ((unsigned)hs[3] << 16);
        hv.z = (unsigned)hs[4] | ((unsigned)hs[5] << 16);
        hv.w = (unsigned)hs[6] | ((unsigned)hs[7] << 16);
        lv.x = (unsigned)ls[0] | ((unsigned)ls[1] << 16);
        lv.y = (unsigned)ls[2] | ((unsigned)ls[3] << 16);
        lv.z = (unsigned)ls[4] | ((unsigned)ls[5] << 16);
        lv.w = (unsigned)ls[6] | ((unsigned)ls[7] << 16);
        *reinterpret_cast<uint4*>(xh + ((size_t)c * NPIX + p) * 8) = hv;
        *reinterpret_cast<uint4*>(xl + ((size_t)c * NPIX + p) * 8) = lv;
    }
}

// MFMA filter: per wave 16 pixels x 512 codes. cb frags staged in LDS in 4
// groups of 8 tiles (4 waves share one L2 read). dot = xh*eh + xh*el + xl*eh.
// (round-9 verbatim -- the 77 us champion; R13-R16 established that every
// "slimmer" variant is strictly slower -- FROZEN)
__global__ __launch_bounds__(256) void vq_mfma(const unsigned short* __restrict__ xh,
        const unsigned short* __restrict__ xl, const unsigned short* __restrict__ cbfh,
        const unsigned short* __restrict__ cbfl, const float* __restrict__ t1a,
        const float* __restrict__ ck, int* __restrict__ idx,
        int* __restrict__ count, int* __restrict__ list) {
    __shared__ unsigned short sh[8192];   // 16 KB: 8 tiles x 2 ksteps x 512
    __shared__ unsigned short sl[8192];   // 16 KB

    const int t    = threadIdx.x;
    const int lane = t & 63;
    const int wu   = __builtin_amdgcn_readfirstlane(t >> 6);
    const int P0   = blockIdx.x * 64 + wu * 16;
    const int n    = lane & 15;          // A-row / B-col / D-col index
    const int g    = lane >> 4;          // k-block / D-row group
    const int pp   = P0 + n;

    const bf16x8 ah0 = *(const bf16x8*)(xh + ((size_t)g       * NPIX + pp) * 8);
    const bf16x8 ah1 = *(const bf16x8*)(xh + ((size_t)(g + 4) * NPIX + pp) * 8);
    const bf16x8 al0 = *(const bf16x8*)(xl + ((size_t)g       * NPIX + pp) * 8);
    const bf16x8 al1 = *(const bf16x8*)(xl + ((size_t)(g + 4) * NPIX + pp) * 8);
    const f32x4 t1v = *(const f32x4*)(t1a + P0 + g * 4);

    float best[4], best2[4];
    int besti[4];
    #pragma unroll
    for (int i = 0; i < 4; ++i) { best[i] = FLT_MAX; best2[i] = FLT_MAX; besti[i] = 0x7fffffff; }

    #pragma unroll 1
    for (int G = 0; G < 4; ++G) {
        // stage 8 tiles of frag-packed cb (16 KB h + 16 KB l), coalesced uint4
        {
            const uint4* srcH = (const uint4*)(cbfh + G * 8192);
            const uint4* srcL = (const uint4*)(cbfl + G * 8192);
            uint4* dstH = (uint4*)sh;
            uint4* dstL = (uint4*)sl;
            #pragma unroll
            for (int i = 0; i < 4; ++i) {
                dstH[t + i * 256] = srcH[t + i * 256];
                dstL[t + i * 256] = srcL[t + i * 256];
            }
        }
        __syncthreads();

        #pragma unroll 2
        for (int tl = 0; tl < 8; ++tl) {
            const int tile = G * 8 + tl;
            const int b0 = tl * 1024 + g * 128 + n * 8;
            const bf16x8 bh0 = *(const bf16x8*)(sh + b0);
            const bf16x8 bh1 = *(const bf16x8*)(sh + b0 + 512);
            const bf16x8 bl0 = *(const bf16x8*)(sl + b0);
            const bf16x8 bl1 = *(const bf16x8*)(sl + b0 + 512);
            const float ckv = ck[tile * 16 + n];

            f32x4 acc0 = {0.f, 0.f, 0.f, 0.f};
            f32x4 acc1 = {0.f, 0.f, 0.f, 0.f};
            acc0 = __builtin_amdgcn_mfma_f32_16x16x32_bf16(al0, bh0, acc0, 0, 0, 0);
            acc1 = __builtin_amdgcn_mfma_f32_16x16x32_bf16(al1, bh1, acc1, 0, 0, 0);
            acc0 = __builtin_amdgcn_mfma_f32_16x16x32_bf16(ah0, bl0, acc0, 0, 0, 0);
            acc1 = __builtin_amdgcn_mfma_f32_16x16x32_bf16(ah1, bl1, acc1, 0, 0, 0);
            acc0 = __builtin_amdgcn_mfma_f32_16x16x32_bf16(ah0, bh0, acc0, 0, 0, 0);
            acc1 = __builtin_amdgcn_mfma_f32_16x16x32_bf16(ah1, bh1, acc1, 0, 0, 0);

            const int kbase = tile * 16 + n;
            #pragma unroll
            for (int i = 0; i < 4; ++i) {
                const float dot  = acc0[i] + acc1[i];
                const float u    = fmaf(-2.0f, dot, t1v[i]);
                const float dist = u + ckv;
                if (dist < best[i]) { best2[i] = best[i]; best[i] = dist; besti[i] = kbase; }
                else if (dist == best[i]) { best2[i] = dist; if (kbase < besti[i]) besti[i] = kbase; }
                else if (dist < best2[i]) { best2[i] = dist; }
            }
        }
        __syncthreads();
    }

    // merge the 16 lanes of each row-group (each holds different code columns)
    #pragma unroll
    for (int off = 1; off < 16; off <<= 1) {
        #pragma unroll
        for (int i = 0; i < 4; ++i) {
            const float ob  = __shfl_xor(best[i],  off, 16);
            const float ob2 = __shfl_xor(best2[i], off, 16);
            const int   obi = __shfl_xor(besti[i], off, 16);
            if (ob < best[i])      { best2[i] = fminf(best[i], ob2); best[i] = ob; besti[i] = obi; }
            else if (ob > best[i]) { best2[i] = fminf(best2[i], ob); }
            else { besti[i] = min(besti[i], obi); best2[i] = fminf(fminf(best2[i], ob2), ob); }
        }
    }

    if (n == 0) {
        #pragma unroll
        for (int i = 0; i < 4; ++i) {
            const int p = P0 + g * 4 + i;
            idx[p] = besti[i];
            if (best2[i] - best[i] < GT) {
                const int slot = atomicAdd(count, 1);
                list[slot] = p;
            }
        }
    }
}

// Exact numpy rescore for near-tie pixels (round-9 verbatim, uses t1a).
__global__ __launch_bounds__(256) void vq_refine(const float* __restrict__ enc,
        const float* __restrict__ cb, const float* __restrict__ ck,
        const float* __restrict__ t1a, const int* __restrict__ count,
        const int* __restrict__ list, int* __restrict__ idx) {
    const int nref = *count;
    const int lane = threadIdx.x & 63;
    const int gw   = (int)((blockIdx.x * blockDim.x + threadIdx.x) >> 6);
    const int nw   = (int)((gridDim.x * blockDim.x) >> 6);
    for (int r = gw; r < nref; r += nw) {
        const int p  = list[r];
        const int b  = p >> 12;
        const int hw = p & 4095;
        const float* xp = enc + (size_t)b * (D * HW) + hw;
        const float xown = xp[(size_t)lane * HW];   // lane holds x[lane]
        const float t1 = t1a[p];
        float acc[8];
        #pragma unroll
        for (int j = 0; j < 8; ++j) acc[j] = 0.f;
        const float* cbl = cb + lane * 8;
        #pragma unroll 16
        for (int d = 0; d < D; ++d) {
            const float xd = __shfl(xown, d);
            const float4 c0 = *(const float4*)(cbl + (size_t)d * K);
            const float4 c1 = *(const float4*)(cbl + (size_t)d * K + 4);
            acc[0] = fmaf(xd, c0.x, acc[0]);
            acc[1] = fmaf(xd, c0.y, acc[1]);
            acc[2] = fmaf(xd, c0.z, acc[2]);
            acc[3] = fmaf(xd, c0.w, acc[3]);
            acc[4] = fmaf(xd, c1.x, acc[4]);
            acc[5] = fmaf(xd, c1.y, acc[5]);
            acc[6] = fmaf(xd, c1.z, acc[6]);
            acc[7] = fmaf(xd, c1.w, acc[7]);
        }
        float bv = FLT_MAX;
        int bI = 0x7fffffff;
        #pragma unroll
        for (int j = 0; j < 8; ++j) {
            const float u    = fmaf(-2.0f, acc[j], t1);
            const float dist = u + ck[lane * 8 + j];
            if (dist < bv) { bv = dist; bI = lane * 8 + j; }
        }
        #pragma unroll
        for (int off = 32; off > 0; off >>= 1) {
            const float ov = __shfl_down(bv, off);
            const int   oi = __shfl_down(bI, off);
            if (ov < bv || (ov == bv && oi < bI)) { bv = ov; bI = oi; }
        }
        if (lane == 0) idx[p] = bI;
    }
}

// ===== scalar fallback (round-7, proven 128 us) =====
__global__ void vq_prep_s(const float* __restrict__ cb, float* __restrict__ ck) {
#pragma clang fp contract(off)
    const int k = threadIdx.x;
    float s = 0.f;
    for (int d = 0; d < D; ++d) {
        const float e  = cb[d * K + k];
        const float e2 = e * e;
        s = s + e2;
    }
    ck[k] = s;
}

__global__ __launch_bounds__(256, 8) void vq_main_s(const float* __restrict__ enc,
        const float* __restrict__ cb, const float* __restrict__ ck,
        int* __restrict__ idx) {
    __shared__ float xs[D][64];
    __shared__ float bvs[3][64];
    __shared__ int   bis[3][64];

    const int t    = threadIdx.x;
    const int lane = t & 63;
    const int wu   = __builtin_amdgcn_readfirstlane(t >> 6);
    const int base = blockIdx.x * 64;
    const int b    = base >> 12;
    const int hw0  = base & 4095;
    const float* ep = enc + (size_t)b * (D * HW) + hw0;

    #pragma unroll
    for (int i = 0; i < 16; ++i) {
        const int id  = t + i * 256;
        xs[id >> 6][id & 63] = ep[(size_t)(id >> 6) * HW + (id & 63)];
    }
    __syncthreads();

    float t1;
    {
#pragma clang fp contract(off)
        float r[8];
        #pragma unroll
        for (int j = 0; j < 8; ++j) { const float v = xs[j][lane]; r[j] = v * v; }
        #pragma unroll
        for (int i = 8; i < 64; i += 8) {
            #pragma unroll
            for (int j = 0; j < 8; ++j) {
                const float v = xs[i + j][lane]; const float v2 = v * v; r[j] = r[j] + v2;
            }
        }
        t1 = ((r[0] + r[1]) + (r[2] + r[3])) + ((r[4] + r[5]) + (r[6] + r[7]));
    }

    float best = FLT_MAX;
    int besti  = 0x7fffffff;
    const int kbase = wu * (K / 4);
    #pragma unroll 1
    for (int tt = 0; tt < 8; ++tt) {
        const int k0 = kbase + tt * KT;
        float acc[KT];
        #pragma unroll
        for (int j = 0; j < KT; ++j) acc[j] = 0.f;
        #pragma unroll 8
        for (int d = 0; d < D; ++d) {
            const float xv = xs[d][lane];
            const float* cbrow = cb + d * K + k0;
            #pragma unroll
            for (int j = 0; j < KT; ++j) acc[j] = fmaf(xv, cbrow[j], acc[j]);
        }
        #pragma unroll
        for (int j = 0; j < KT; ++j) {
            const float u    = fmaf(-2.0f, acc[j], t1);
            const float dist = u + ck[k0 + j];
            if (dist < best) { best = dist; besti = k0 + j; }
        }
    }

    if (wu > 0) { bvs[wu - 1][lane] = best; bis[wu - 1][lane] = besti; }
    __syncthreads();
    if (wu == 0) {
        #pragma unroll
        for (int q = 0; q < 3; ++q) {
            const float ov = bvs[q][lane];
            const int   oi = bis[q][lane];
            if (ov < best) { best = ov; besti = oi; }
        }
        idx[base + lane] = besti;
    }
}

__global__ void vq_out(const float* __restrict__ cb, const int* __restrict__ idx,
                       float* __restrict__ out) {
    const int o = (blockIdx.x * 256 + threadIdx.x) * 4;
    const int d = (o >> 12) & 63;
    const int bhw = ((o >> 18) << 12) | (o & 4095);
    const int4 iv = *reinterpret_cast<const int4*>(idx + bhw);
    float4 v;
    v.x = cb[d * K + iv.x];
    v.y = cb[d * K + iv.y];
    v.z = cb[d * K + iv.z];
    v.w = cb[d * K + iv.w];
    *reinterpret_cast<float4*>(out + o) = v;
}

extern "C" void kernel_launch(void* const* d_in, const int* in_sizes, int n_in,
                              void* d_out, int out_size, void* d_ws, size_t ws_size,
                              hipStream_t stream) {
    const float* enc = (const float*)d_in[0];
    const float* cb  = (const float*)d_in[1];
    float* out = (float*)d_out;
    char* ws = (char*)d_ws;

    if (ws_size >= (size_t)WS_NEED) {
        float*          ck   = (float*)(ws + OFF_CK);
        unsigned short* cbfh = (unsigned short*)(ws + OFF_CBFH);
        unsigned short* cbfl = (unsigned short*)(ws + OFF_CBFL);
        float*          t1a  = (float*)(ws + OFF_T1);
        unsigned short* xh   = (unsigned short*)(ws + OFF_XH);
        unsigned short* xl   = (unsigned short*)(ws + OFF_XL);
        int*            idx  = (int*)(ws + OFF_IDX);
        int*            cnt  = (int*)(ws + OFF_CNT);
        int*            list = (int*)(ws + OFF_LIST);

        vq_prep_pre<<<2 + NPIX / 256, 256, 0, stream>>>(cb, enc, ck, cbfh, cbfl,
                                                        cnt, t1a, xh, xl);
        vq_mfma<<<NPIX / 64, 256, 0, stream>>>(xh, xl, cbfh, cbfl, t1a, ck, idx, cnt, list);
        vq_refine<<<1024, 256, 0, stream>>>(enc, cb, ck, t1a, cnt, list, idx);
        vq_out<<<out_size / 1024, 256, 0, stream>>>(cb, idx, out);
    } else {
        float* ck  = (float*)ws;
        int*   idx = (int*)(ws + 2048);
        vq_prep_s<<<1, K, 0, stream>>>(cb, ck);
        vq_main_s<<<NPIX / 64, 256, 0, stream>>>(enc, cb, ck, idx);
        vq_out<<<out_size / 1024, 256, 0, stream>>>(cb, idx, out);
    }
}